// Round 6
// baseline (122.707 us; speedup 1.0000x reference)
//
#include <hip/hip_runtime.h>

#define NB 4096
#define SS 102
#define QSCALE 0.72134752044448170368f  // 0.5 * log2(e)

typedef float v2f __attribute__((ext_vector_type(2)));
typedef __fp16 h2 __attribute__((ext_vector_type(2)));
typedef __fp16 h8 __attribute__((ext_vector_type(8)));

// LDS map (bytes):
//  RAW  0..9792      f32 [3][102][8] raw q/k/v rows.
//       Aliased after the projection barrier:
//         COMB f32 [102][8]          at 0..3264
//         PART f32 [2][52][10]       at 3264..7424  (k-split partials)
//  QF   9792..13120  f32 [2][104][4] rotated+prescaled q (rows 102/103 = 0)
//  ROT  13120..13936 f32 [102][2]    (sin(s), cos(s))
//  KV   13936..17264 f16 [2][104][8] interleaved: K d0..3 | V d0..3 per key
__global__ __launch_bounds__(256) void mha_fused_kernel(
    const float* __restrict__ query, const float* __restrict__ key,
    const float* __restrict__ value, const float* __restrict__ wq,
    const float* __restrict__ wk, const float* __restrict__ wvp,
    const float* __restrict__ wo, float* __restrict__ out)
{
    __shared__ __align__(16) unsigned char lds[17264];
    float*  RAW  = (float*)lds;
    float*  QF   = (float*)(lds + 9792);
    float*  ROTT = (float*)(lds + 13120);
    __fp16* KV   = (__fp16*)(lds + 13936);
    float*  COMB = (float*)lds;           // alias (valid after barrier 2)
    float*  PART = (float*)(lds + 3264);  // alias (valid after barrier 2)

    const int t = threadIdx.x;
    const int b = blockIdx.x;

    // ---- issue global loads into registers ----
    float4 rq, rk, rv;
    if (t < 204) {
        const float4* q4 = (const float4*)(query + (size_t)b * 816);
        const float4* k4 = (const float4*)(key   + (size_t)b * 816);
        const float4* v4 = (const float4*)(value + (size_t)b * 816);
        rq = q4[t]; rk = k4[t]; rv = v4[t];
    }

    // ---- independent work overlapping global-load latency ----
    if (t < SS) {                         // rotary table (reference quirk:
        const float ang = (float)t;       //  head0 uses sin(s), head1 cos(s))
        ROTT[2 * t]     = sinf(ang);
        ROTT[2 * t + 1] = cosf(ang);
    }
    if (t >= 208 && t < 212) {            // zero QF pad rows 102/103, both heads
        const int z = t - 208;
        *(float4*)(QF + (((z >> 1) * 104) + SS + (z & 1)) * 4) =
            (float4){0.f, 0.f, 0.f, 0.f};
    }

    // ---- commit staged raw rows ----
    if (t < 204) {
        float4* R4 = (float4*)RAW;
        R4[t]       = rq;
        R4[204 + t] = rk;
        R4[408 + t] = rv;
    }
    __syncthreads();   // barrier 1

    // ---- projections: one wave per tensor (0=q,1=k,2=v), one thread per row.
    // Weights are wave-uniform -> SGPR s_loads; zero LDS traffic for weights.
    {
        const int wvu  = __builtin_amdgcn_readfirstlane(t >> 6);
        const int lane = t & 63;
        if (wvu < 3) {
            const float* W = (wvu == 0) ? wq : (wvu == 1) ? wk : wvp;
            for (int r = lane; r < SS; r += 64) {
                const float4 a = *(const float4*)(RAW + (wvu * SS + r) * 8);
                const float4 c = *(const float4*)(RAW + (wvu * SS + r) * 8 + 4);
                float x[8];
#pragma unroll
                for (int ch = 0; ch < 8; ++ch) {
                    x[ch] = a.x * W[ch * 8 + 0] + a.y * W[ch * 8 + 1]
                          + a.z * W[ch * 8 + 2] + a.w * W[ch * 8 + 3]
                          + c.x * W[ch * 8 + 4] + c.y * W[ch * 8 + 5]
                          + c.z * W[ch * 8 + 6] + c.w * W[ch * 8 + 7];
                }
                if (wvu == 2) {           // v: f16 halves into KV records
#pragma unroll
                    for (int h = 0; h < 2; ++h) {
                        __fp16* rec = KV + (h * 104 + r) * 8;
                        *(h2*)(rec + 4) = __builtin_amdgcn_cvt_pkrtz(x[4*h+0], x[4*h+1]);
                        *(h2*)(rec + 6) = __builtin_amdgcn_cvt_pkrtz(x[4*h+2], x[4*h+3]);
                    }
                } else {                  // q/k: fused rotary
                    const float2 sc = *(const float2*)(ROTT + 2 * r);
#pragma unroll
                    for (int h = 0; h < 2; ++h) {
                        float w = (h == 0) ? sc.x : sc.y;
                        if (wvu == 0) w *= QSCALE;
                        const float y0 = (x[4*h+0] - x[4*h+1]) * w;
                        const float y1 = (x[4*h+1] + x[4*h+0]) * w;
                        const float y2 = (x[4*h+2] - x[4*h+3]) * w;
                        const float y3 = (x[4*h+3] + x[4*h+2]) * w;
                        if (wvu == 0) {
                            *(float4*)(QF + (h * 104 + r) * 4) =
                                (float4){y0, y1, y2, y3};
                        } else {
                            __fp16* rec = KV + (h * 104 + r) * 8;
                            *(h2*)(rec)     = __builtin_amdgcn_cvt_pkrtz(y0, y1);
                            *(h2*)(rec + 2) = __builtin_amdgcn_cvt_pkrtz(y2, y3);
                        }
                    }
                }
            }
        }
    }
    __syncthreads();   // barrier 2 (RAW dead -> COMB/PART aliases valid)

    // ---- attention: wave = (head, key-half); 2 q-rows per lane (52 active).
    // One ds_read_b128 per key fetches K and V together (f16 interleaved).
    {
        const int wv   = t >> 6, lane = t & 63;
        const int h    = wv >> 1, kh = wv & 1;
        const bool act = lane < 52;
        v2f acc0 = {0.f, 0.f}, acc1 = {0.f, 0.f},
            acc2 = {0.f, 0.f}, acc3 = {0.f, 0.f}, L = {0.f, 0.f};
        if (act) {
            const float4 qa = *(const float4*)(QF + (h * 104 + 2 * lane) * 4);
            const float4 qc = *(const float4*)(QF + (h * 104 + 2 * lane + 1) * 4);
            const v2f q0 = {qa.x, qc.x}, q1 = {qa.y, qc.y},
                      q2 = {qa.z, qc.z}, q3 = {qa.w, qc.w};
            const __fp16* KVh = KV + (h * 104 + kh * 51) * 8;
            for (int j = 0; j < 51; ++j) {
                const h8 rec = *(const h8*)(KVh + j * 8);
                const float k0 = (float)rec[0], k1 = (float)rec[1];
                const float k2 = (float)rec[2], k3 = (float)rec[3];
                const float v0 = (float)rec[4], v1 = (float)rec[5];
                const float v2 = (float)rec[6], v3 = (float)rec[7];
                v2f s = q0 * k0 + q1 * k1 + q2 * k2 + q3 * k3;
                v2f p;
                p.x = __builtin_amdgcn_exp2f(s.x);
                p.y = __builtin_amdgcn_exp2f(s.y);
                L += p;
                acc0 += p * v0; acc1 += p * v1;
                acc2 += p * v2; acc3 += p * v3;
            }
            if (kh == 1) {   // publish partials (PART aliases dead RAW)
                float* P = PART + (h * 52 + lane) * 10;
                *(v2f*)(P + 0) = acc0; *(v2f*)(P + 2) = acc1;
                *(v2f*)(P + 4) = acc2; *(v2f*)(P + 6) = acc3;
                *(v2f*)(P + 8) = L;
            }
        }
        __syncthreads();   // barrier 3
        if (act && kh == 0) {
            const float* P = PART + (h * 52 + lane) * 10;
            acc0 += *(const v2f*)(P + 0); acc1 += *(const v2f*)(P + 2);
            acc2 += *(const v2f*)(P + 4); acc3 += *(const v2f*)(P + 6);
            L    += *(const v2f*)(P + 8);
            const float a0[2] = {acc0.x, acc0.y}, a1[2] = {acc1.x, acc1.y};
            const float a2[2] = {acc2.x, acc2.y}, a3[2] = {acc3.x, acc3.y};
            const float ll[2] = {L.x, L.y};
#pragma unroll
            for (int j = 0; j < 2; ++j) {
                const int row = 2 * lane + j;
                if (row < SS) {
                    const float inv = 1.f / ll[j];
                    *(float4*)(COMB + row * 8 + h * 4) =
                        (float4){a0[j] * inv, a1[j] * inv, a2[j] * inv, a3[j] * inv};
                }
            }
        }
    }
    __syncthreads();   // barrier 4

    // ---- output projection (wo in SGPRs) + vectorized global store ----
    if (t < SS) {
        const float4 a = *(const float4*)(COMB + t * 8);
        const float4 c = *(const float4*)(COMB + t * 8 + 4);
        float x[8];
#pragma unroll
        for (int ch = 0; ch < 8; ++ch) {
            x[ch] = a.x * wo[ch * 8 + 0] + a.y * wo[ch * 8 + 1]
                  + a.z * wo[ch * 8 + 2] + a.w * wo[ch * 8 + 3]
                  + c.x * wo[ch * 8 + 4] + c.y * wo[ch * 8 + 5]
                  + c.z * wo[ch * 8 + 6] + c.w * wo[ch * 8 + 7];
        }
        float* o = out + (size_t)b * 816 + t * 8;
        *(float4*)(o)     = (float4){x[0], x[1], x[2], x[3]};
        *(float4*)(o + 4) = (float4){x[4], x[5], x[6], x[7]};
    }
}

extern "C" void kernel_launch(void* const* d_in, const int* in_sizes, int n_in,
                              void* d_out, int out_size, void* d_ws, size_t ws_size,
                              hipStream_t stream) {
    const float* query = (const float*)d_in[0];
    const float* key   = (const float*)d_in[1];
    const float* value = (const float*)d_in[2];
    const float* wq    = (const float*)d_in[3];
    const float* wk    = (const float*)d_in[4];
    const float* wv    = (const float*)d_in[5];
    const float* wo    = (const float*)d_in[6];
    float* out = (float*)d_out;
    mha_fused_kernel<<<NB, 256, 0, stream>>>(query, key, value, wq, wk, wv, wo, out);
}

// Round 7
// 119.984 us; speedup vs baseline: 1.0227x; 1.0227x over previous
//
#include <hip/hip_runtime.h>

#define NB 4096
#define SS 102
#define QSCALE 0.72134752044448170368f  // 0.5 * log2(e)

typedef float v2f __attribute__((ext_vector_type(2)));
typedef __fp16 h2 __attribute__((ext_vector_type(2)));
typedef __fp16 h8 __attribute__((ext_vector_type(8)));

// LDS map (bytes):
//  RAW  0..9792      f32 [3][102][8] raw q/k/v rows.
//       Aliased after the projection barrier:
//         COMB f32 [102][8]          at 0..3264
//         PART f32 [2][52][10]       at 3264..7424  (k-split partials)
//  QF   9792..13120  f32 [2][104][4] rotated+prescaled q (rows 102/103 = 0)
//  ROT  13120..13936 f32 [102][2]    (sin(s), cos(s))
//  KV   13936..17264 f16 [2][104][8] interleaved: K d0..3 | V d0..3 per key
__global__ __launch_bounds__(256) void mha_fused_kernel(
    const float* __restrict__ query, const float* __restrict__ key,
    const float* __restrict__ value, const float* __restrict__ wq,
    const float* __restrict__ wk, const float* __restrict__ wvp,
    const float* __restrict__ wo, float* __restrict__ out)
{
    __shared__ __align__(16) unsigned char lds[17264];
    float*  RAW  = (float*)lds;
    float*  QF   = (float*)(lds + 9792);
    float*  ROTT = (float*)(lds + 13120);
    __fp16* KV   = (__fp16*)(lds + 13936);
    float*  COMB = (float*)lds;           // alias (valid after barrier 2)
    float*  PART = (float*)(lds + 3264);  // alias (valid after barrier 2)

    const int t = threadIdx.x;
    const int b = blockIdx.x;

    // ---- issue global loads into registers ----
    float4 rq, rk, rv;
    if (t < 204) {
        const float4* q4 = (const float4*)(query + (size_t)b * 816);
        const float4* k4 = (const float4*)(key   + (size_t)b * 816);
        const float4* v4 = (const float4*)(value + (size_t)b * 816);
        rq = q4[t]; rk = k4[t]; rv = v4[t];
    }

    // ---- independent work overlapping global-load latency ----
    if (t < SS) {                         // rotary table (reference quirk:
        const float ang = (float)t;       //  head0 uses sin(s), head1 cos(s))
        ROTT[2 * t]     = sinf(ang);
        ROTT[2 * t + 1] = cosf(ang);
    }
    if (t >= 208 && t < 212) {            // zero QF pad rows 102/103, both heads
        const int z = t - 208;
        *(float4*)(QF + (((z >> 1) * 104) + SS + (z & 1)) * 4) =
            (float4){0.f, 0.f, 0.f, 0.f};
    }

    // ---- commit staged raw rows ----
    if (t < 204) {
        float4* R4 = (float4*)RAW;
        R4[t]       = rq;
        R4[204 + t] = rk;
        R4[408 + t] = rv;
    }
    __syncthreads();   // barrier 1

    // ---- projections: one wave per tensor (0=q,1=k,2=v), one thread per row.
    // Weights are wave-uniform -> SGPR s_loads; zero LDS traffic for weights.
    {
        const int wvu  = __builtin_amdgcn_readfirstlane(t >> 6);
        const int lane = t & 63;
        if (wvu < 3) {
            const float* W = (wvu == 0) ? wq : (wvu == 1) ? wk : wvp;
            for (int r = lane; r < SS; r += 64) {
                const float4 a = *(const float4*)(RAW + (wvu * SS + r) * 8);
                const float4 c = *(const float4*)(RAW + (wvu * SS + r) * 8 + 4);
                float x[8];
#pragma unroll
                for (int ch = 0; ch < 8; ++ch) {
                    x[ch] = a.x * W[ch * 8 + 0] + a.y * W[ch * 8 + 1]
                          + a.z * W[ch * 8 + 2] + a.w * W[ch * 8 + 3]
                          + c.x * W[ch * 8 + 4] + c.y * W[ch * 8 + 5]
                          + c.z * W[ch * 8 + 6] + c.w * W[ch * 8 + 7];
                }
                if (wvu == 2) {           // v: f16 halves into KV records
#pragma unroll
                    for (int h = 0; h < 2; ++h) {
                        __fp16* rec = KV + (h * 104 + r) * 8;
                        *(h2*)(rec + 4) = __builtin_amdgcn_cvt_pkrtz(x[4*h+0], x[4*h+1]);
                        *(h2*)(rec + 6) = __builtin_amdgcn_cvt_pkrtz(x[4*h+2], x[4*h+3]);
                    }
                } else {                  // q/k: fused rotary
                    const float2 sc = *(const float2*)(ROTT + 2 * r);
#pragma unroll
                    for (int h = 0; h < 2; ++h) {
                        float w = (h == 0) ? sc.x : sc.y;
                        if (wvu == 0) w *= QSCALE;
                        const float y0 = (x[4*h+0] - x[4*h+1]) * w;
                        const float y1 = (x[4*h+1] + x[4*h+0]) * w;
                        const float y2 = (x[4*h+2] - x[4*h+3]) * w;
                        const float y3 = (x[4*h+3] + x[4*h+2]) * w;
                        if (wvu == 0) {
                            *(float4*)(QF + (h * 104 + r) * 4) =
                                (float4){y0, y1, y2, y3};
                        } else {
                            __fp16* rec = KV + (h * 104 + r) * 8;
                            *(h2*)(rec)     = __builtin_amdgcn_cvt_pkrtz(y0, y1);
                            *(h2*)(rec + 2) = __builtin_amdgcn_cvt_pkrtz(y2, y3);
                        }
                    }
                }
            }
        }
    }
    __syncthreads();   // barrier 2 (RAW dead -> COMB/PART aliases valid)

    // ---- attention: wave = (head, key-half); 2 q-rows per lane (52 active).
    // One ds_read_b128 per key fetches K and V together (f16 interleaved).
    // QK via v_dot2_f32_f16 (q pre-converted to h2), PV via v_fma_mix_f32
    // (compiler matches fpext(f16) in the FMA).
    {
        const int wv   = t >> 6, lane = t & 63;
        const int h    = wv >> 1, kh = wv & 1;
        const bool act = lane < 52;
        float aA0 = 0.f, aA1 = 0.f, aA2 = 0.f, aA3 = 0.f, lA = 0.f;
        float aB0 = 0.f, aB1 = 0.f, aB2 = 0.f, aB3 = 0.f, lB = 0.f;
        if (act) {
            const float4 qa = *(const float4*)(QF + (h * 104 + 2 * lane) * 4);
            const float4 qc = *(const float4*)(QF + (h * 104 + 2 * lane + 1) * 4);
            const h2 qA01 = __builtin_amdgcn_cvt_pkrtz(qa.x, qa.y);
            const h2 qA23 = __builtin_amdgcn_cvt_pkrtz(qa.z, qa.w);
            const h2 qB01 = __builtin_amdgcn_cvt_pkrtz(qc.x, qc.y);
            const h2 qB23 = __builtin_amdgcn_cvt_pkrtz(qc.z, qc.w);
            const __fp16* KVh = KV + (h * 104 + kh * 51) * 8;
#pragma unroll 3
            for (int j = 0; j < 51; ++j) {
                const h8 rec = *(const h8*)(KVh + j * 8);
                const h2 k01 = {rec[0], rec[1]};
                const h2 k23 = {rec[2], rec[3]};
                const float sA = __builtin_amdgcn_fdot2(
                    k01, qA01, __builtin_amdgcn_fdot2(k23, qA23, 0.f, false), false);
                const float sB = __builtin_amdgcn_fdot2(
                    k01, qB01, __builtin_amdgcn_fdot2(k23, qB23, 0.f, false), false);
                const float pA = __builtin_amdgcn_exp2f(sA);
                const float pB = __builtin_amdgcn_exp2f(sB);
                lA += pA; lB += pB;
                aA0 += pA * (float)rec[4]; aA1 += pA * (float)rec[5];
                aA2 += pA * (float)rec[6]; aA3 += pA * (float)rec[7];
                aB0 += pB * (float)rec[4]; aB1 += pB * (float)rec[5];
                aB2 += pB * (float)rec[6]; aB3 += pB * (float)rec[7];
            }
            if (kh == 1) {   // publish partials (PART aliases dead RAW)
                float* P = PART + (h * 52 + lane) * 10;
                P[0] = aA0; P[1] = aA1; P[2] = aA2; P[3] = aA3; P[4] = lA;
                P[5] = aB0; P[6] = aB1; P[7] = aB2; P[8] = aB3; P[9] = lB;
            }
        }
        __syncthreads();   // barrier 3
        if (act && kh == 0) {
            const float* P = PART + (h * 52 + lane) * 10;
            aA0 += P[0]; aA1 += P[1]; aA2 += P[2]; aA3 += P[3]; lA += P[4];
            aB0 += P[5]; aB1 += P[6]; aB2 += P[7]; aB3 += P[8]; lB += P[9];
            const int rowA = 2 * lane, rowB = 2 * lane + 1;
            {
                const float inv = 1.f / lA;
                *(float4*)(COMB + rowA * 8 + h * 4) =
                    (float4){aA0 * inv, aA1 * inv, aA2 * inv, aA3 * inv};
            }
            if (rowB < SS) {
                const float inv = 1.f / lB;
                *(float4*)(COMB + rowB * 8 + h * 4) =
                    (float4){aB0 * inv, aB1 * inv, aB2 * inv, aB3 * inv};
            }
        }
    }
    __syncthreads();   // barrier 4

    // ---- output projection (wo in SGPRs) + vectorized global store ----
    if (t < SS) {
        const float4 a = *(const float4*)(COMB + t * 8);
        const float4 c = *(const float4*)(COMB + t * 8 + 4);
        float x[8];
#pragma unroll
        for (int ch = 0; ch < 8; ++ch) {
            x[ch] = a.x * wo[ch * 8 + 0] + a.y * wo[ch * 8 + 1]
                  + a.z * wo[ch * 8 + 2] + a.w * wo[ch * 8 + 3]
                  + c.x * wo[ch * 8 + 4] + c.y * wo[ch * 8 + 5]
                  + c.z * wo[ch * 8 + 6] + c.w * wo[ch * 8 + 7];
        }
        float* o = out + (size_t)b * 816 + t * 8;
        *(float4*)(o)     = (float4){x[0], x[1], x[2], x[3]};
        *(float4*)(o + 4) = (float4){x[4], x[5], x[6], x[7]};
    }
}

extern "C" void kernel_launch(void* const* d_in, const int* in_sizes, int n_in,
                              void* d_out, int out_size, void* d_ws, size_t ws_size,
                              hipStream_t stream) {
    const float* query = (const float*)d_in[0];
    const float* key   = (const float*)d_in[1];
    const float* value = (const float*)d_in[2];
    const float* wq    = (const float*)d_in[3];
    const float* wk    = (const float*)d_in[4];
    const float* wv    = (const float*)d_in[5];
    const float* wo    = (const float*)d_in[6];
    float* out = (float*)d_out;
    mha_fused_kernel<<<NB, 256, 0, stream>>>(query, key, value, wq, wk, wv, wo, out);
}